// Round 15
// baseline (257.941 us; speedup 1.0000x reference)
//
#include <hip/hip_runtime.h>
#include <hip/hip_fp16.h>
#include <cstdint>
#include <cmath>

// GCN, 4 layers. Structure: A(hW) = (Ah)W with norm folded into features:
//   g = dis (.) h  stored FP16,
//   A_norm h [d] = dis[d] * ( sum_e w_e * g[src_e] + g[d] )
// CSR via two-level LDS counting sort (R12). Layers wave-autonomous (R13).
//
// R15: R14's packed-fp16 accum REVERTED (218us vs R13's 208: VALUBusy fell
// 46->36% yet time rose + 5M conflicts returned -> kernel is gather-LATENCY
// bound, not VALU bound). This round keeps R13 code exactly and adds the one
// latency lever: dual-node interleave in phase 1 -- each 8-lane group owns
// TWO nodes (block = 64 nodes), main loop issues 2+2 independent gathers from
// two chains -> 2x outstanding loads/thread, tail imbalance averaged over 2
// nodes. Wave-autonomy kept (wave's groups write the 16 rows its two phase-2
// passes read). bucket_init dispatch -> hipMemsetAsync.

#define NPB_SHIFT 9
#define NPB 512              // nodes per bucket
#define CHUNK 4096           // edges per block in count/scatter passes

// ---- fdot2: 2x f16 MAC with fp32 accumulator (guarded builtin)
__device__ __forceinline__ float fdot2f(__half2 a, __half2 b, float c) {
#if defined(__has_builtin)
#if __has_builtin(__builtin_amdgcn_fdot2)
    typedef _Float16 h2v __attribute__((ext_vector_type(2)));
    return __builtin_amdgcn_fdot2(__builtin_bit_cast(h2v, a),
                                  __builtin_bit_cast(h2v, b), c, false);
#else
    float2 fa = __half22float2(a), fb = __half22float2(b);
    return fmaf(fa.x, fb.x, fmaf(fa.y, fb.y, c));
#endif
#else
    float2 fa = __half22float2(a), fb = __half22float2(b);
    return fmaf(fa.x, fb.x, fmaf(fa.y, fb.y, c));
#endif
}

// ---- wave-local LDS fence: all this wave's ds_writes visible to its ds_reads
__device__ __forceinline__ void wave_lds_fence() {
    asm volatile("s_waitcnt lgkmcnt(0)" ::: "memory");
    __builtin_amdgcn_wave_barrier();
    __builtin_amdgcn_sched_barrier(0);
}

// ------------------------------------------- CSR build: two-level counting sort

__global__ __launch_bounds__(256) void bucket_count_kernel(const int* __restrict__ dst,
                                                           int* __restrict__ bucket_cnt,
                                                           int* __restrict__ blockbase,
                                                           int nbuck, int E) {
    __shared__ int hist[256];
    int tid = threadIdx.x;
    hist[tid] = 0;
    __syncthreads();
    int base = blockIdx.x * CHUNK;
    #pragma unroll
    for (int u = 0; u < CHUNK / 256; ++u) {
        int e = base + u * 256 + tid;
        if (e < E) atomicAdd(&hist[dst[e] >> NPB_SHIFT], 1);
    }
    __syncthreads();
    if (tid < nbuck)
        blockbase[blockIdx.x * nbuck + tid] = atomicAdd(&bucket_cnt[tid], hist[tid]);
}

__global__ __launch_bounds__(64) void bucket_scan_kernel(const int* __restrict__ bucket_cnt,
                                                         int* __restrict__ bucket_base,
                                                         int nbuck, int E) {
    int lane = threadIdx.x;
    int run = 0;
    for (int b0 = 0; b0 < nbuck; b0 += 64) {
        int i = b0 + lane;
        int v = (i < nbuck) ? bucket_cnt[i] : 0;
        int x = v;
        #pragma unroll
        for (int off = 1; off < 64; off <<= 1) {
            int t = __shfl_up(x, off);
            if (lane >= off) x += t;
        }
        if (i < nbuck) bucket_base[i] = run + x - v;
        run += __shfl(x, 63);
    }
    if (lane == 0) bucket_base[nbuck] = E;
}

__global__ __launch_bounds__(256) void bucket_scatter_kernel(const int* __restrict__ src,
                                                             const int* __restrict__ dst,
                                                             const float* __restrict__ w,
                                                             const int* __restrict__ bucket_base,
                                                             const int* __restrict__ blockbase,
                                                             int2* __restrict__ temp,
                                                             int nbuck, int E) {
    __shared__ int cursor[256];
    int tid = threadIdx.x;
    if (tid < nbuck)
        cursor[tid] = bucket_base[tid] + blockbase[blockIdx.x * nbuck + tid];
    __syncthreads();
    int base = blockIdx.x * CHUNK;
    #pragma unroll
    for (int u = 0; u < CHUNK / 256; ++u) {
        int e = base + u * 256 + tid;
        if (e < E) {
            int d = dst[e];
            int pos = atomicAdd(&cursor[d >> NPB_SHIFT], 1);
            temp[pos] = make_int2(src[e] | ((d & (NPB - 1)) << 17),
                                  __float_as_int(w[e]));
        }
    }
}

__global__ __launch_bounds__(256) void bucket_csr_kernel(const int2* __restrict__ temp,
                                                         const int* __restrict__ bucket_base,
                                                         int* __restrict__ offsets,
                                                         int2* __restrict__ pairs,
                                                         int n, int E) {
    __shared__ int cnt[NPB];
    __shared__ int wtot[4];
    int tid = threadIdx.x;
    int bk = blockIdx.x;
    int base = bucket_base[bk], end = bucket_base[bk + 1];
    cnt[tid] = 0; cnt[tid + 256] = 0;
    __syncthreads();
    for (int j = base + tid; j < end; j += 256)
        atomicAdd(&cnt[temp[j].x >> 17], 1);
    __syncthreads();
    int a0 = cnt[2 * tid], a1 = cnt[2 * tid + 1];
    int s = a0 + a1;
    int lane = tid & 63, wid = tid >> 6;
    int x = s;
    #pragma unroll
    for (int off = 1; off < 64; off <<= 1) {
        int t2 = __shfl_up(x, off);
        if (lane >= off) x += t2;
    }
    if (lane == 63) wtot[wid] = x;
    __syncthreads();
    int wbase = 0;
    #pragma unroll
    for (int wv = 0; wv < 4; ++wv) if (wv < wid) wbase += wtot[wv];
    int e0 = wbase + x - s;
    int abs0 = base + e0, abs1 = base + e0 + a0;
    int node0 = bk * NPB + 2 * tid;
    if (node0 < n)     offsets[node0]     = abs0;
    if (node0 + 1 < n) offsets[node0 + 1] = abs1;
    __syncthreads();
    cnt[2 * tid] = abs0; cnt[2 * tid + 1] = abs1;
    __syncthreads();
    for (int j = base + tid; j < end; j += 256) {
        int2 t2 = temp[j];
        int pos = atomicAdd(&cnt[t2.x >> 17], 1);
        pairs[pos] = make_int2(t2.x & 0x1FFFF, t2.y);
    }
    if (bk == 0 && tid == 0) offsets[n] = E;
}

// fused: deg row-sum -> dis -> g0 = fp16(dis (.) x). 16 lanes per node.
__global__ __launch_bounds__(256) void rowsum_scale_kernel(const int* __restrict__ offsets,
                                                           const int2* __restrict__ pairs,
                                                           const float* __restrict__ x,
                                                           float* __restrict__ dis,
                                                           __half* __restrict__ g, int n) {
    int node = blockIdx.x * 16 + (threadIdx.x >> 4);
    int q = threadIdx.x & 15;
    if (node >= n) return;
    int j0 = offsets[node], end = offsets[node + 1];
    float s = 0.f;
    for (int j = j0 + q; j < end; j += 16) s += __int_as_float(pairs[j].y);
    #pragma unroll
    for (int off = 8; off; off >>= 1) s += __shfl_xor(s, off);
    float dn = rsqrtf(1.0f + s);
    if (q == 0) dis[node] = dn;
    float4 v = reinterpret_cast<const float4*>(x)[(size_t)node * 16 + q];
    __half2 pk[2];
    pk[0] = __float22half2_rn(make_float2(dn * v.x, dn * v.y));
    pk[1] = __float22half2_rn(make_float2(dn * v.z, dn * v.w));
    reinterpret_cast<float2*>(g + (size_t)node * 64)[q] = *reinterpret_cast<float2*>(pk);
}

// ---------------------------------------------------------------- aggregation core
__device__ __forceinline__ void accum8(float* acc, float4 rv, float w) {
    const __half2* h = reinterpret_cast<const __half2*>(&rv);
    #pragma unroll
    for (int k = 0; k < 4; ++k) {
        float2 f = __half22float2(h[k]);
        acc[2 * k]     = fmaf(w, f.x, acc[2 * k]);
        acc[2 * k + 1] = fmaf(w, f.y, acc[2 * k + 1]);
    }
}

__device__ __forceinline__ void agg_tail(const float4* __restrict__ gt,
                                         const int2* __restrict__ pairs,
                                         int j, int end, int q,
                                         float* __restrict__ acc) {
    for (; j + 4 <= end; j += 4) {
        int2 p0 = pairs[j], p1 = pairs[j + 1], p2 = pairs[j + 2], p3 = pairs[j + 3];
        float4 r0 = gt[(size_t)p0.x * 8 + q];
        float4 r1 = gt[(size_t)p1.x * 8 + q];
        float4 r2 = gt[(size_t)p2.x * 8 + q];
        float4 r3 = gt[(size_t)p3.x * 8 + q];
        accum8(acc, r0, __int_as_float(p0.y));
        accum8(acc, r1, __int_as_float(p1.y));
        accum8(acc, r2, __int_as_float(p2.y));
        accum8(acc, r3, __int_as_float(p3.y));
    }
    for (; j < end; ++j) {
        int2 p = pairs[j];
        float4 r = gt[(size_t)p.x * 8 + q];
        accum8(acc, r, __int_as_float(p.y));
    }
}

// ---- phase 1 dual: each 8-lane group aggregates TWO nodes (A = base+g,
// B = base+32+g) with interleaved 2+2 gathers -> 4 independent loads in
// flight per thread across two chains. Writes rows[g] and rows[32+g].
__device__ __forceinline__ void phase1_agg_dual(const __half* __restrict__ gin,
                                                const float* __restrict__ dis,
                                                const int* __restrict__ offsets,
                                                const int2* __restrict__ pairs,
                                                __half2 (*rows)[33], int n, int tid,
                                                int base_node) {
    int g = tid >> 3;
    int q = tid & 7;
    int nA = base_node + g;
    int nB = base_node + 32 + g;
    const float4* gt = reinterpret_cast<const float4*>(gin);

    float accA[8] = {0.f, 0.f, 0.f, 0.f, 0.f, 0.f, 0.f, 0.f};
    float accB[8] = {0.f, 0.f, 0.f, 0.f, 0.f, 0.f, 0.f, 0.f};
    int jA = 0, eA = 0, jB = 0, eB = 0;
    if (nA < n) { jA = offsets[nA]; eA = offsets[nA + 1]; }
    if (nB < n) { jB = offsets[nB]; eB = offsets[nB + 1]; }

    // joint main loop: 2 edges from each chain per iteration
    while (jA + 2 <= eA && jB + 2 <= eB) {
        int2 a0 = pairs[jA], a1 = pairs[jA + 1];
        int2 b0 = pairs[jB], b1 = pairs[jB + 1];
        float4 rA0 = gt[(size_t)a0.x * 8 + q];
        float4 rA1 = gt[(size_t)a1.x * 8 + q];
        float4 rB0 = gt[(size_t)b0.x * 8 + q];
        float4 rB1 = gt[(size_t)b1.x * 8 + q];
        accum8(accA, rA0, __int_as_float(a0.y));
        accum8(accA, rA1, __int_as_float(a1.y));
        accum8(accB, rB0, __int_as_float(b0.y));
        accum8(accB, rB1, __int_as_float(b1.y));
        jA += 2; jB += 2;
    }
    agg_tail(gt, pairs, jA, eA, q, accA);
    agg_tail(gt, pairs, jB, eB, q, accB);

    if (nA < n) {
        float4 rs = gt[(size_t)nA * 8 + q];          // self term, weight 1
        accum8(accA, rs, 1.0f);
        float dn = dis[nA];
        #pragma unroll
        for (int k2 = 0; k2 < 4; ++k2)
            rows[g][q * 4 + k2] =
                __float22half2_rn(make_float2(dn * accA[2 * k2], dn * accA[2 * k2 + 1]));
    }
    if (nB < n) {
        float4 rs = gt[(size_t)nB * 8 + q];
        accum8(accB, rs, 1.0f);
        float dn = dis[nB];
        #pragma unroll
        for (int k2 = 0; k2 < 4; ++k2)
            rows[32 + g][q * 4 + k2] =
                __float22half2_rn(make_float2(dn * accB[2 * k2], dn * accB[2 * k2 + 1]));
    }
}

// -------------------------------- fused layer 1-3: aggregate -> GEMM64+ELU -> fp16
// Block = 64 nodes. Phase 2 = two passes of the R13-proven mapping
// (node2 = pass*32 + wave*8 + (lane&7), slice = lane>>3). Wave-autonomous.
__global__ __launch_bounds__(256) void layer_fused_kernel(const __half* __restrict__ gin,
                                                          const float* __restrict__ dis,
                                                          const int* __restrict__ offsets,
                                                          const int2* __restrict__ pairs,
                                                          const float* __restrict__ W,
                                                          const float* __restrict__ b,
                                                          __half* __restrict__ gout, int n) {
    __shared__ __half2 rows[64][33];
    __shared__ __half2 WT[64][33];   // WT[c][k2] = (W[2k2][c], W[2k2+1][c]) fp16
    __shared__ float bias_s[64];
    for (int idx = threadIdx.x; idx < 64 * 32; idx += 256) {
        int k2 = idx >> 6, c = idx & 63;
        WT[c][k2] = __float22half2_rn(make_float2(W[(2 * k2) * 64 + c],
                                                  W[(2 * k2 + 1) * 64 + c]));
    }
    if (threadIdx.x < 64) bias_s[threadIdx.x] = b[threadIdx.x];
    __syncthreads();          // WT/bias ready (only block barrier)

    int tid = threadIdx.x;
    phase1_agg_dual(gin, dis, offsets, pairs, rows, n, tid, blockIdx.x * 64);
    wave_lds_fence();         // this wave's rows visible to this wave

    int lane  = tid & 63, wave = tid >> 6;
    int slice = lane >> 3;                 // 0..7 -> outputs [8*slice, 8*slice+8)
    #pragma unroll
    for (int pass = 0; pass < 2; ++pass) {
        int node2  = pass * 32 + wave * 8 + (lane & 7);
        int gnode2 = blockIdx.x * 64 + node2;
        if (gnode2 < n) {
            __half2 h2[32];
            #pragma unroll
            for (int i = 0; i < 32; ++i) h2[i] = rows[node2][i];
            float dn = dis[gnode2];
            int c0 = slice * 8;
            float r[8];
            #pragma unroll
            for (int cc = 0; cc < 8; ++cc) {
                const __half2* wt = &WT[c0 + cc][0];
                float a0 = 0.f, a1 = 0.f, a2 = 0.f, a3 = 0.f;
                #pragma unroll
                for (int i = 0; i < 8; ++i) {
                    a0 = fdot2f(h2[4 * i],     wt[4 * i],     a0);
                    a1 = fdot2f(h2[4 * i + 1], wt[4 * i + 1], a1);
                    a2 = fdot2f(h2[4 * i + 2], wt[4 * i + 2], a2);
                    a3 = fdot2f(h2[4 * i + 3], wt[4 * i + 3], a3);
                }
                float v = (a0 + a1) + (a2 + a3) + bias_s[c0 + cc];
                v = (v > 0.f) ? v : expm1f(v);          // ELU
                r[cc] = dn * v;                          // pre-scale for next layer
            }
            __half2 pk[4];
            pk[0] = __float22half2_rn(make_float2(r[0], r[1]));
            pk[1] = __float22half2_rn(make_float2(r[2], r[3]));
            pk[2] = __float22half2_rn(make_float2(r[4], r[5]));
            pk[3] = __float22half2_rn(make_float2(r[6], r[7]));
            *reinterpret_cast<float4*>(gout + (size_t)gnode2 * 64 + c0) =
                *reinterpret_cast<float4*>(pk);
        }
    }
}

// ------------- fused layer 4 (R13-proven form, 32 nodes/block):
// aggregate -> GEMM40 -> log_softmax -> d_out
__device__ __forceinline__ void phase1_agg(const __half* __restrict__ gin,
                                           const float* __restrict__ dis,
                                           const int* __restrict__ offsets,
                                           const int2* __restrict__ pairs,
                                           __half2 (*rows)[33], int n, int tid,
                                           int blockbase_node) {
    int ln = tid >> 3;
    int q  = tid & 7;
    int gnode = blockbase_node + ln;
    if (gnode < n) {
        const float4* gt = reinterpret_cast<const float4*>(gin);
        float acc[8] = {0.f, 0.f, 0.f, 0.f, 0.f, 0.f, 0.f, 0.f};
        agg_tail(gt, pairs, offsets[gnode], offsets[gnode + 1], q, acc);
        float4 rs = gt[(size_t)gnode * 8 + q];   // self term, weight 1
        accum8(acc, rs, 1.0f);
        float dn = dis[gnode];
        #pragma unroll
        for (int k2 = 0; k2 < 4; ++k2)
            rows[ln][q * 4 + k2] =
                __float22half2_rn(make_float2(dn * acc[2 * k2], dn * acc[2 * k2 + 1]));
    }
}

__global__ __launch_bounds__(256) void layer4_fused_kernel(const __half* __restrict__ gin,
                                                           const float* __restrict__ dis,
                                                           const int* __restrict__ offsets,
                                                           const int2* __restrict__ pairs,
                                                           const float* __restrict__ W,
                                                           const float* __restrict__ b,
                                                           float* __restrict__ out, int n) {
    __shared__ __half2 rows[32][33];
    __shared__ __half2 WT[40][33];
    __shared__ float bias_s[40];
    for (int idx = threadIdx.x; idx < 40 * 32; idx += 256) {
        int c = idx % 40, k2 = idx / 40;
        WT[c][k2] = __float22half2_rn(make_float2(W[(2 * k2) * 40 + c],
                                                  W[(2 * k2 + 1) * 40 + c]));
    }
    if (threadIdx.x < 40) bias_s[threadIdx.x] = b[threadIdx.x];
    __syncthreads();

    int tid = threadIdx.x;
    phase1_agg(gin, dis, offsets, pairs, rows, n, tid, blockIdx.x * 32);
    wave_lds_fence();

    int lane  = tid & 63, wave = tid >> 6;
    int node2 = wave * 8 + (lane & 7);
    int slice = lane >> 3;                 // classes [5*slice, 5*slice+5)
    int gnode2 = blockIdx.x * 32 + node2;

    float r[5];
    float mp = -__builtin_inff();
    if (gnode2 < n) {
        __half2 h2[32];
        #pragma unroll
        for (int i = 0; i < 32; ++i) h2[i] = rows[node2][i];
        int c0 = slice * 5;
        #pragma unroll
        for (int cc = 0; cc < 5; ++cc) {
            const __half2* wt = &WT[c0 + cc][0];
            float a0 = 0.f, a1 = 0.f, a2 = 0.f, a3 = 0.f;
            #pragma unroll
            for (int i = 0; i < 8; ++i) {
                a0 = fdot2f(h2[4 * i],     wt[4 * i],     a0);
                a1 = fdot2f(h2[4 * i + 1], wt[4 * i + 1], a1);
                a2 = fdot2f(h2[4 * i + 2], wt[4 * i + 2], a2);
                a3 = fdot2f(h2[4 * i + 3], wt[4 * i + 3], a3);
            }
            r[cc] = (a0 + a1) + (a2 + a3) + bias_s[c0 + cc];
            mp = fmaxf(mp, r[cc]);
        }
    }
    // row max/sum over the 8 slices (lanes node2, node2+8, ..., node2+56)
    mp = fmaxf(mp, __shfl_xor(mp, 8));
    mp = fmaxf(mp, __shfl_xor(mp, 16));
    mp = fmaxf(mp, __shfl_xor(mp, 32));
    float sp = 0.f;
    if (gnode2 < n) {
        #pragma unroll
        for (int cc = 0; cc < 5; ++cc) sp += expf(r[cc] - mp);
    }
    sp += __shfl_xor(sp, 8);
    sp += __shfl_xor(sp, 16);
    sp += __shfl_xor(sp, 32);
    if (gnode2 < n) {
        float ls = logf(sp) + mp;
        float* outp = out + (size_t)gnode2 * 40 + slice * 5;
        #pragma unroll
        for (int cc = 0; cc < 5; ++cc) outp[cc] = r[cc] - ls;
    }
}

// ---------------------------------------------------------------- launch

static inline size_t align_up(size_t x, size_t a) { return (x + a - 1) & ~(a - 1); }

extern "C" void kernel_launch(void* const* d_in, const int* in_sizes, int n_in,
                              void* d_out, int out_size, void* d_ws, size_t ws_size,
                              hipStream_t stream) {
    const float* x  = (const float*)d_in[0];
    const int*   ei = (const int*)d_in[1];     // [2][E] flat: src then dst
    const float* ea = (const float*)d_in[2];
    const float* W1 = (const float*)d_in[3];
    const float* b1 = (const float*)d_in[4];
    const float* W2 = (const float*)d_in[5];
    const float* b2 = (const float*)d_in[6];
    const float* W3 = (const float*)d_in[7];
    const float* b3 = (const float*)d_in[8];
    const float* W4 = (const float*)d_in[9];
    const float* b4 = (const float*)d_in[10];

    const int N = in_sizes[0] / 64;
    const int E = in_sizes[1] / 2;

    const int* src = ei;
    const int* dst = ei + E;

    const int nbuck   = (N + NPB - 1) >> NPB_SHIFT;      // 196 for N=100K (<=256)
    const int nblk_ac = (E + CHUNK - 1) / CHUNK;         // 293

    // workspace carve-up
    char* p = (char*)d_ws;
    int*    offsets     = (int*)p;  p += align_up(((size_t)N + 1) * 4, 256);
    int*    bucket_cnt  = (int*)p;  p += align_up(((size_t)nbuck + 1) * 4, 256);
    int*    bucket_base = (int*)p;  p += align_up(((size_t)nbuck + 1) * 4, 256);
    int*    blockbase   = (int*)p;  p += align_up((size_t)nblk_ac * nbuck * 4, 256);
    float*  dis         = (float*)p; p += align_up((size_t)N * 4, 256);
    int2*   pairs       = (int2*)p;  p += align_up(((size_t)E + 8) * 8, 256);
    int2*   temp        = (int2*)p;  p += align_up(((size_t)E + 8) * 8, 256);
    __half* gA          = (__half*)p; p += align_up((size_t)N * 64 * 2, 256);
    __half* gB          = (__half*)p; p += align_up((size_t)N * 64 * 2, 256);
    (void)ws_size;

    const int nb_g16 = (N + 15) / 16;
    const int nb_f   = (N + 63) / 64;           // layer1-3: 64 nodes/block
    const int nb_f4  = (N + 31) / 32;           // layer4: 32 nodes/block

    // --- CSR build (two-level counting sort, LDS-privatized) ---
    hipMemsetAsync(bucket_cnt, 0, (size_t)(nbuck + 1) * 4, stream);
    bucket_count_kernel<<<nblk_ac, 256, 0, stream>>>(dst, bucket_cnt, blockbase, nbuck, E);
    bucket_scan_kernel<<<1, 64, 0, stream>>>(bucket_cnt, bucket_base, nbuck, E);
    bucket_scatter_kernel<<<nblk_ac, 256, 0, stream>>>(src, dst, ea, bucket_base,
                                                       blockbase, temp, nbuck, E);
    bucket_csr_kernel<<<nbuck, 256, 0, stream>>>(temp, bucket_base, offsets, pairs, N, E);
    rowsum_scale_kernel<<<nb_g16, 256, 0, stream>>>(offsets, pairs, x, dis, gA, N);

    // --- layers 1..3 fused (aggregate -> GEMM64+ELU -> fp16), dual-node waves ---
    layer_fused_kernel<<<nb_f, 256, 0, stream>>>(gA, dis, offsets, pairs, W1, b1, gB, N);
    layer_fused_kernel<<<nb_f, 256, 0, stream>>>(gB, dis, offsets, pairs, W2, b2, gA, N);
    layer_fused_kernel<<<nb_f, 256, 0, stream>>>(gA, dis, offsets, pairs, W3, b3, gB, N);

    // --- layer 4 fused: aggregate -> GEMM40 -> log_softmax -> d_out ---
    layer4_fused_kernel<<<nb_f4, 256, 0, stream>>>(gB, dis, offsets, pairs, W4, b4,
                                                   (float*)d_out, N);
}